// Round 4
// baseline (325.225 us; speedup 1.0000x reference)
//
#include <hip/hip_runtime.h>
#include <hip/hip_bf16.h>
#include <stdint.h>
#include <stddef.h>

// ---------------- problem constants ----------------
#define B_ 4
#define T_ 2048
#define C_ 1024
#define H_ 16
#define D_ 64
#define M_ (B_ * T_)   // 8192 rows of x

typedef __bf16 bf16x8 __attribute__((ext_vector_type(8)));
typedef float  f32x4  __attribute__((ext_vector_type(4)));
typedef short  s16x4  __attribute__((ext_vector_type(4)));
typedef unsigned short u16x8 __attribute__((ext_vector_type(8)));
typedef unsigned short u16x4 __attribute__((ext_vector_type(4)));
typedef unsigned int   u32x2 __attribute__((ext_vector_type(2)));

__device__ __forceinline__ unsigned short f2bf(float f) {
    union { float f; unsigned int u; } c; c.f = f;
    unsigned int u = c.u;
    unsigned int r = (u + 0x7fffu + ((u >> 16) & 1u)) >> 16;
    return (unsigned short)r;
}

// pack two f32 -> one dword of 2 bf16 (round-half-up; <=1ulp vs RNE).
// low short = bf(a), high short = bf(b).
__device__ __forceinline__ unsigned int pack2bf(float a, float b) {
    unsigned int ua = __builtin_bit_cast(unsigned int, a) + 0x8000u;
    unsigned int ub = __builtin_bit_cast(unsigned int, b) + 0x8000u;
    // v_perm_b32: sel bytes 0-3 = S1, 4-7 = S0; dest = [ua.b2,ua.b3,ub.b2,ub.b3]
    return __builtin_amdgcn_perm(ub, ua, 0x07060302u);
}

__device__ __forceinline__ bf16x8 ld_bf16x8(const unsigned short* p) {
    u16x8 v = *(const u16x8*)p;
    return __builtin_bit_cast(bf16x8, v);
}

// async global -> LDS, 16 B per lane (dest = uniform base + lane*16)
__device__ __forceinline__ void gl_lds16(const unsigned short* g, unsigned short* l) {
    __builtin_amdgcn_global_load_lds(
        (const void __attribute__((address_space(1)))*)g,
        (void __attribute__((address_space(3)))*)l, 16, 0, 0);
}

__device__ __forceinline__ f32x4 mfma16(s16x4 a, s16x4 b, f32x4 c) {
#if __has_builtin(__builtin_amdgcn_mfma_f32_16x16x16bf16_1k)
    return __builtin_amdgcn_mfma_f32_16x16x16bf16_1k(a, b, c, 0, 0, 0);
#else
    asm volatile("v_mfma_f32_16x16x16_bf16 %0, %1, %2, %0"
                 : "+v"(c) : "v"(a), "v"(b));
    return c;
#endif
}

__device__ __forceinline__ f32x4 vmax4(f32x4 a, f32x4 b) {
    f32x4 r;
    r.x = fmaxf(a.x, b.x); r.y = fmaxf(a.y, b.y);
    r.z = fmaxf(a.z, b.z); r.w = fmaxf(a.w, b.w);
    return r;
}

// ============================================================
// Kernel 0: fp32 -> bf16 conversion of x and {Wq,Wk,Wv} (concat).
// ============================================================
#define X4_ ((int64_t)M_ * C_ / 4)   // 2,097,152 float4s
#define W4_ ((int64_t)C_ * C_ / 4)   //   262,144 float4s per W

__global__ __launch_bounds__(256)
void cvt_bf16(const float* __restrict__ x,
              const float* __restrict__ Wq, const float* __restrict__ Wk,
              const float* __restrict__ Wv,
              unsigned short* __restrict__ xb, unsigned short* __restrict__ wb)
{
    const int64_t i4 = (int64_t)blockIdx.x * blockDim.x + threadIdx.x;
    const float* src; unsigned short* dst; int64_t off;
    if (i4 < X4_) { src = x; dst = xb; off = i4; }
    else {
        int64_t j = i4 - X4_;
        int which = (int)(j / W4_);
        off = j - (int64_t)which * W4_;
        src = (which == 0) ? Wq : (which == 1) ? Wk : Wv;
        dst = wb + (int64_t)which * C_ * C_;
    }
    f32x4 v = *(const f32x4*)(src + off * 4);
    u16x4 o = { f2bf(v.x), f2bf(v.y), f2bf(v.z), f2bf(v.w) };
    *(u16x4*)(dst + off * 4) = o;
}

// ============================================================
// Kernel 1: y = xb @ Wb^T + b, N concat = 3072. Pure bf16.
// BK=64, XOR-chunk-swizzled LDS ([128][64] u16, LDS[r][c]=src[r][c^(r&7)]).
// q stored PRE-SCALED by 0.125*log2(e); v stored [B,H,D,T] with a
// 128-kv-block internal permutation matching flash_attn's PV A-frags.
// ============================================================
#define K1_ 0.180336880f   // 0.125 * log2(e)

__global__ __launch_bounds__(256)
void qkv_gemm(const unsigned short* __restrict__ xb,
              const unsigned short* __restrict__ wb,
              const float* __restrict__ bq, const float* __restrict__ bk,
              const float* __restrict__ bv,
              unsigned short* __restrict__ qo,
              unsigned short* __restrict__ ko,
              unsigned short* __restrict__ vo)
{
    __shared__ alignas(16) unsigned short As[128 * 64];
    __shared__ alignas(16) unsigned short Bs[128 * 64];

    const int tid   = threadIdx.x;
    const int bm    = blockIdx.x;          // 0..63
    const int bn    = blockIdx.y;          // 0..23
    const int which = bn >> 3;             // 0=q 1=k 2=v
    const int n_base = (bn & 7) * 128;
    const int nrow   = bn * 128;
    const int m_base = bm * 128;

    const float* bias = (which == 0) ? bq : (which == 1) ? bk : bv;

    const int w = tid >> 6, lane = tid & 63;
    const int wr = w >> 1, wc = w & 1;
    const int ln = lane & 15, quad = lane >> 4;

    // staging: instr i covers 8 rows of 128 B; swizzled source chunk
    const int srow   = lane >> 3;                  // 0..7
    const int schunk = (lane & 7) ^ srow;          // 0..7
    const int scu    = schunk * 8;

    const f32x4 fz = {0.f, 0.f, 0.f, 0.f};
    f32x4 acc[4][4];
#pragma unroll
    for (int i = 0; i < 4; ++i)
#pragma unroll
        for (int j = 0; j < 4; ++j) acc[i][j] = fz;

    for (int k0 = 0; k0 < C_; k0 += 64) {
        __syncthreads();
#pragma unroll
        for (int i = 0; i < 4; ++i) {
            const int r = w * 32 + i * 8 + srow;
            gl_lds16(xb + (size_t)(m_base + r) * C_ + k0 + scu, As + (w * 4 + i) * 512);
            gl_lds16(wb + (size_t)(nrow  + r) * C_ + k0 + scu, Bs + (w * 4 + i) * 512);
        }
        __syncthreads();

#pragma unroll
        for (int kk = 0; kk < 2; ++kk) {
            bf16x8 af[4], bfr[4];
#pragma unroll
            for (int mi = 0; mi < 4; ++mi) {
                const int r = wr * 64 + mi * 16 + ln;
                af[mi] = ld_bf16x8(&As[r * 64 + (((kk * 4 + quad) ^ (ln & 7)) * 8)]);
            }
#pragma unroll
            for (int ni = 0; ni < 4; ++ni) {
                const int r = wc * 64 + ni * 16 + ln;
                bfr[ni] = ld_bf16x8(&Bs[r * 64 + (((kk * 4 + quad) ^ (ln & 7)) * 8)]);
            }
#pragma unroll
            for (int mi = 0; mi < 4; ++mi)
#pragma unroll
                for (int ni = 0; ni < 4; ++ni)
                    acc[mi][ni] = __builtin_amdgcn_mfma_f32_16x16x32_bf16(
                        af[mi], bfr[ni], acc[mi][ni], 0, 0, 0);
        }
    }

#pragma unroll
    for (int ni = 0; ni < 4; ++ni) {
        const int n_local = n_base + wc * 64 + ni * 16 + ln;   // 0..1023
        const float bv_ = bias[n_local];
        const int h = n_local >> 6, d = n_local & 63;
#pragma unroll
        for (int mi = 0; mi < 4; ++mi) {
            const int m0 = m_base + wr * 64 + mi * 16 + quad * 4;
            const int b  = m0 >> 11;
            const int t0 = m0 & (T_ - 1);
            f32x4 v = acc[mi][ni];
            if (which == 2) {
                // permuted [B,H,D,T]: within each 128-kv block,
                // pos(kv) = (kvt>>1)*32 + quad*8 + (kvt&1)*4 + j, kvt=kv>>4
                const int tb   = t0 & ~127;
                const int w128 = t0 & 127;
                const int kvt  = w128 >> 4;
                const int qd   = (w128 >> 2) & 3;
                const int pos  = (kvt >> 1) * 32 + qd * 8 + (kvt & 1) * 4;
                u16x4 pk = { f2bf(v.x + bv_), f2bf(v.y + bv_),
                             f2bf(v.z + bv_), f2bf(v.w + bv_) };
                *(u16x4*)(&vo[((size_t)(b * H_ + h) * D_ + d) * T_ + tb + pos]) = pk;
            } else if (which == 0) {
                // q pre-scaled by K1_
                unsigned short* dst =
                    qo + ((size_t)(b * H_ + h) * T_ + t0) * (size_t)D_ + d;
                dst[0 * D_] = f2bf((v.x + bv_) * K1_);
                dst[1 * D_] = f2bf((v.y + bv_) * K1_);
                dst[2 * D_] = f2bf((v.z + bv_) * K1_);
                dst[3 * D_] = f2bf((v.w + bv_) * K1_);
            } else {
                unsigned short* dst =
                    ko + ((size_t)(b * H_ + h) * T_ + t0) * (size_t)D_ + d;
                dst[0 * D_] = f2bf(v.x + bv_);
                dst[1 * D_] = f2bf(v.y + bv_);
                dst[2 * D_] = f2bf(v.z + bv_);
                dst[3 * D_] = f2bf(v.w + bv_);
            }
        }
    }
}

// ============================================================
// Kernel 2: flash attention, S^T form, BN=128, log2-domain softmax.
// Ks [128][64] swizzled; Vs [64][128] in PV-frag permuted order so
// each (dt,p) A-frag pair is ONE broadcast ds_read_b128.
// ============================================================
__global__ __launch_bounds__(256)
void flash_attn(const unsigned short* __restrict__ qb,
                const unsigned short* __restrict__ kb,
                const unsigned short* __restrict__ vtb,
                float* __restrict__ out)
{
    __shared__ alignas(16) unsigned char smem[32768];
    unsigned short* Ks = (unsigned short*)smem;              // [128][64] swz
    unsigned short* Vs = (unsigned short*)(smem + 16384);    // [64][128] perm
    float* Os = (float*)smem;                                // [64][68] epilogue

    const int tid = threadIdx.x;
    const int qt  = blockIdx.x;   // 0..31
    const int bh  = blockIdx.y;   // 0..63
    const int b   = bh >> 4, h = bh & 15;

    const int w = tid >> 6, lane = tid & 63;
    const int ln = lane & 15, quad = lane >> 4;

    const unsigned short* Qb = qb  + (size_t)bh * T_ * D_;
    const unsigned short* Kb = kb  + (size_t)bh * T_ * D_;
    const unsigned short* Vb = vtb + (size_t)bh * D_ * T_;

    // Q (pre-scaled) as B-operand fragments
    const int qrow = qt * 64 + w * 16 + ln;
    const bf16x8 qf0 = ld_bf16x8(&Qb[(size_t)qrow * D_ + quad * 8]);
    const bf16x8 qf1 = ld_bf16x8(&Qb[(size_t)qrow * D_ + 32 + quad * 8]);

    // K staging: instr i -> 8 rows of 128B, swizzled chunks
    const int srow   = lane >> 3;
    const int schunk = (lane & 7) ^ srow;
    const int scu    = schunk * 8;
    // V staging: instr i -> 4 rows of 256B, linear
    const int vrow = lane >> 4;          // 0..3
    const int vcu  = (lane & 15) * 8;

    const f32x4 fz = {0.f, 0.f, 0.f, 0.f};
    float m2 = -3.0e38f, l_i = 0.f;
    f32x4 acc[4];                 // O^T: row d = dt*16+quad*4+r, col q = ln
#pragma unroll
    for (int dt = 0; dt < 4; ++dt) acc[dt] = fz;

    for (int kv0 = 0; kv0 < T_; kv0 += 128) {
        __syncthreads();
#pragma unroll
        for (int i = 0; i < 4; ++i) {
            const int kr = kv0 + w * 32 + i * 8 + srow;
            gl_lds16(Kb + (size_t)kr * D_ + scu, Ks + (w * 4 + i) * 512);
            const int dr = w * 16 + i * 4 + vrow;
            gl_lds16(Vb + (size_t)dr * T_ + kv0 + vcu, Vs + (w * 4 + i) * 512);
        }
        __syncthreads();

        // S^T = K · Q^T  (already includes 1/sqrt(D)*log2e via Q)
        f32x4 s[8];
#pragma unroll
        for (int kvt = 0; kvt < 8; ++kvt) {
            const int r_ = kvt * 16 + ln;               // r_&7 == ln&7
            bf16x8 kf0 = ld_bf16x8(&Ks[r_ * 64 + ((quad)     ^ (ln & 7)) * 8]);
            bf16x8 kf1 = ld_bf16x8(&Ks[r_ * 64 + ((quad + 4) ^ (ln & 7)) * 8]);
            f32x4 c = fz;
            c = __builtin_amdgcn_mfma_f32_16x16x32_bf16(kf0, qf0, c, 0, 0, 0);
            c = __builtin_amdgcn_mfma_f32_16x16x32_bf16(kf1, qf1, c, 0, 0, 0);
            s[kvt] = c;
        }

        // online softmax (log2 domain)
        f32x4 mm = vmax4(vmax4(vmax4(s[0], s[1]), vmax4(s[2], s[3])),
                         vmax4(vmax4(s[4], s[5]), vmax4(s[6], s[7])));
        float mx = fmaxf(fmaxf(mm.x, mm.y), fmaxf(mm.z, mm.w));
        mx = fmaxf(mx, __shfl_xor(mx, 16));
        mx = fmaxf(mx, __shfl_xor(mx, 32));

        const float nm = fmaxf(m2, mx);
        const float alpha = __builtin_amdgcn_exp2f(m2 - nm);
        m2 = nm;

        f32x4 rsv = fz;
        s16x4 pk[8];
#pragma unroll
        for (int kvt = 0; kvt < 8; ++kvt) {
            f32x4 pv;
            pv.x = __builtin_amdgcn_exp2f(s[kvt].x - m2);
            pv.y = __builtin_amdgcn_exp2f(s[kvt].y - m2);
            pv.z = __builtin_amdgcn_exp2f(s[kvt].z - m2);
            pv.w = __builtin_amdgcn_exp2f(s[kvt].w - m2);
            rsv += pv;
            u32x2 pd = { pack2bf(pv.x, pv.y), pack2bf(pv.z, pv.w) };
            pk[kvt] = __builtin_bit_cast(s16x4, pd);
        }
        float rs = (rsv.x + rsv.y) + (rsv.z + rsv.w);
        rs += __shfl_xor(rs, 16);
        rs += __shfl_xor(rs, 32);
        l_i = l_i * alpha + rs;

#pragma unroll
        for (int dt = 0; dt < 4; ++dt) acc[dt] *= alpha;

        // O^T += V^T · P^T ; V frags: one broadcast b128 per (dt, kvt-pair)
#pragma unroll
        for (int dt = 0; dt < 4; ++dt) {
            const int vr = dt * 16 + ln;
#pragma unroll
            for (int p = 0; p < 4; ++p) {
                u16x8 vv = *(const u16x8*)(&Vs[vr * 128 + (p * 4 + quad) * 8]);
                s16x4 v0 = { (short)vv[0], (short)vv[1], (short)vv[2], (short)vv[3] };
                s16x4 v1 = { (short)vv[4], (short)vv[5], (short)vv[6], (short)vv[7] };
                acc[dt] = mfma16(v0, pk[2 * p],     acc[dt]);
                acc[dt] = mfma16(v1, pk[2 * p + 1], acc[dt]);
            }
        }
    }

    // epilogue: normalize, transpose O^T -> O via LDS, coalesced stores
    __syncthreads();
    const float rinv = 1.0f / l_i;
#pragma unroll
    for (int dt = 0; dt < 4; ++dt)
#pragma unroll
        for (int r = 0; r < 4; ++r)
            Os[(w * 16 + ln) * 68 + dt * 16 + quad * 4 + r] = acc[dt][r] * rinv;
    __syncthreads();

    const int q  = tid >> 2;
    const int c0 = (tid & 3) * 16;
    const float* src = &Os[q * 68 + c0];
    float* dst = &out[((size_t)(b * T_ + qt * 64 + q)) * C_ + h * 64 + c0];
#pragma unroll
    for (int i = 0; i < 4; ++i)
        *(f32x4*)(dst + i * 4) = *(const f32x4*)(src + i * 4);
}

// ============================================================
extern "C" void kernel_launch(void* const* d_in, const int* in_sizes, int n_in,
                              void* d_out, int out_size, void* d_ws, size_t ws_size,
                              hipStream_t stream) {
    const float* q_x = (const float*)d_in[0];
    const float* Wq  = (const float*)d_in[1];
    const float* bq  = (const float*)d_in[2];
    const float* Wk  = (const float*)d_in[3];
    const float* bk  = (const float*)d_in[4];
    const float* Wv  = (const float*)d_in[5];
    const float* bv  = (const float*)d_in[6];
    float* out = (float*)d_out;

    const size_t elems = (size_t)M_ * C_;      // 8,388,608
    unsigned short* xb  = (unsigned short*)d_ws;
    unsigned short* wb  = xb + elems;                    // 3*C*C
    unsigned short* qb  = wb + (size_t)3 * C_ * C_;
    unsigned short* kb  = qb + elems;
    unsigned short* vtb = kb + elems;
    (void)ws_size; (void)in_sizes; (void)n_in; (void)out_size;

    const int64_t total4 = X4_ + 3 * W4_;      // 2,883,584
    cvt_bf16<<<(int)(total4 / 256), 256, 0, stream>>>(q_x, Wq, Wk, Wv, xb, wb);

    qkv_gemm<<<dim3(M_ / 128, 24), 256, 0, stream>>>(
        xb, wb, bq, bk, bv, qb, kb, vtb);

    flash_attn<<<dim3(T_ / 64, B_ * H_), 256, 0, stream>>>(qb, kb, vtb, out);
}

// Round 5
// 292.847 us; speedup vs baseline: 1.1106x; 1.1106x over previous
//
#include <hip/hip_runtime.h>
#include <hip/hip_bf16.h>
#include <stdint.h>
#include <stddef.h>

// ---------------- problem constants ----------------
#define B_ 4
#define T_ 2048
#define C_ 1024
#define H_ 16
#define D_ 64
#define M_ (B_ * T_)   // 8192 rows of x

typedef __bf16 bf16x8 __attribute__((ext_vector_type(8)));
typedef float  f32x4  __attribute__((ext_vector_type(4)));
typedef short  s16x4  __attribute__((ext_vector_type(4)));
typedef unsigned short u16x8 __attribute__((ext_vector_type(8)));
typedef unsigned short u16x4 __attribute__((ext_vector_type(4)));
typedef unsigned int   u32x2 __attribute__((ext_vector_type(2)));

__device__ __forceinline__ unsigned short f2bf(float f) {
    union { float f; unsigned int u; } c; c.f = f;
    unsigned int u = c.u;
    unsigned int r = (u + 0x7fffu + ((u >> 16) & 1u)) >> 16;
    return (unsigned short)r;
}

// pack two f32 -> one dword of 2 bf16 (round-half-up; <=1ulp vs RNE).
__device__ __forceinline__ unsigned int pack2bf(float a, float b) {
    unsigned int ua = __builtin_bit_cast(unsigned int, a) + 0x8000u;
    unsigned int ub = __builtin_bit_cast(unsigned int, b) + 0x8000u;
    return __builtin_amdgcn_perm(ub, ua, 0x07060302u);
}

__device__ __forceinline__ bf16x8 ld_bf16x8(const unsigned short* p) {
    u16x8 v = *(const u16x8*)p;
    return __builtin_bit_cast(bf16x8, v);
}

// async global -> LDS, 16 B per lane (dest = uniform base + lane*16)
__device__ __forceinline__ void gl_lds16(const unsigned short* g, unsigned short* l) {
    __builtin_amdgcn_global_load_lds(
        (const void __attribute__((address_space(1)))*)g,
        (void __attribute__((address_space(3)))*)l, 16, 0, 0);
}

__device__ __forceinline__ f32x4 mfma16(s16x4 a, s16x4 b, f32x4 c) {
#if __has_builtin(__builtin_amdgcn_mfma_f32_16x16x16bf16_1k)
    return __builtin_amdgcn_mfma_f32_16x16x16bf16_1k(a, b, c, 0, 0, 0);
#else
    asm volatile("v_mfma_f32_16x16x16_bf16 %0, %1, %2, %0"
                 : "+v"(c) : "v"(a), "v"(b));
    return c;
#endif
}

__device__ __forceinline__ f32x4 vmax4(f32x4 a, f32x4 b) {
    f32x4 r;
    r.x = fmaxf(a.x, b.x); r.y = fmaxf(a.y, b.y);
    r.z = fmaxf(a.z, b.z); r.w = fmaxf(a.w, b.w);
    return r;
}

// ============================================================
// Kernel 0: fp32 -> bf16 conversion of x and {Wq,Wk,Wv} (concat).
// ============================================================
#define X4_ ((int64_t)M_ * C_ / 4)   // 2,097,152 float4s
#define W4_ ((int64_t)C_ * C_ / 4)   //   262,144 float4s per W

__global__ __launch_bounds__(256)
void cvt_bf16(const float* __restrict__ x,
              const float* __restrict__ Wq, const float* __restrict__ Wk,
              const float* __restrict__ Wv,
              unsigned short* __restrict__ xb, unsigned short* __restrict__ wb)
{
    const int64_t i4 = (int64_t)blockIdx.x * blockDim.x + threadIdx.x;
    const float* src; unsigned short* dst; int64_t off;
    if (i4 < X4_) { src = x; dst = xb; off = i4; }
    else {
        int64_t j = i4 - X4_;
        int which = (int)(j / W4_);
        off = j - (int64_t)which * W4_;
        src = (which == 0) ? Wq : (which == 1) ? Wk : Wv;
        dst = wb + (int64_t)which * C_ * C_;
    }
    f32x4 v = *(const f32x4*)(src + off * 4);
    u16x4 o = { f2bf(v.x), f2bf(v.y), f2bf(v.z), f2bf(v.w) };
    *(u16x4*)(dst + off * 4) = o;
}

// ============================================================
// Kernel 1: y = xb @ Wb^T + b, N concat = 3072. Pure bf16.
// BK=64, XOR-chunk-swizzled LDS ([128][64] u16, LDS[r][c]=src[r][c^(r&7)]).
// q stored PRE-SCALED by 0.125*log2(e); v stored [B,H,D,T] with a
// 128-kv-block internal permutation matching flash_attn's PV A-frags.
// ============================================================
#define K1_ 0.180336880f   // 0.125 * log2(e)

__global__ __launch_bounds__(256)
void qkv_gemm(const unsigned short* __restrict__ xb,
              const unsigned short* __restrict__ wb,
              const float* __restrict__ bq, const float* __restrict__ bk,
              const float* __restrict__ bv,
              unsigned short* __restrict__ qo,
              unsigned short* __restrict__ ko,
              unsigned short* __restrict__ vo)
{
    __shared__ alignas(16) unsigned short As[128 * 64];
    __shared__ alignas(16) unsigned short Bs[128 * 64];

    const int tid   = threadIdx.x;
    const int bm    = blockIdx.x;          // 0..63
    const int bn    = blockIdx.y;          // 0..23
    const int which = bn >> 3;             // 0=q 1=k 2=v
    const int n_base = (bn & 7) * 128;
    const int nrow   = bn * 128;
    const int m_base = bm * 128;

    const float* bias = (which == 0) ? bq : (which == 1) ? bk : bv;

    const int w = tid >> 6, lane = tid & 63;
    const int wr = w >> 1, wc = w & 1;
    const int ln = lane & 15, quad = lane >> 4;

    const int srow   = lane >> 3;                  // 0..7
    const int schunk = (lane & 7) ^ srow;          // 0..7
    const int scu    = schunk * 8;

    const f32x4 fz = {0.f, 0.f, 0.f, 0.f};
    f32x4 acc[4][4];
#pragma unroll
    for (int i = 0; i < 4; ++i)
#pragma unroll
        for (int j = 0; j < 4; ++j) acc[i][j] = fz;

    for (int k0 = 0; k0 < C_; k0 += 64) {
        __syncthreads();
#pragma unroll
        for (int i = 0; i < 4; ++i) {
            const int r = w * 32 + i * 8 + srow;
            gl_lds16(xb + (size_t)(m_base + r) * C_ + k0 + scu, As + (w * 4 + i) * 512);
            gl_lds16(wb + (size_t)(nrow  + r) * C_ + k0 + scu, Bs + (w * 4 + i) * 512);
        }
        __syncthreads();

#pragma unroll
        for (int kk = 0; kk < 2; ++kk) {
            bf16x8 af[4], bfr[4];
#pragma unroll
            for (int mi = 0; mi < 4; ++mi) {
                const int r = wr * 64 + mi * 16 + ln;
                af[mi] = ld_bf16x8(&As[r * 64 + (((kk * 4 + quad) ^ (ln & 7)) * 8)]);
            }
#pragma unroll
            for (int ni = 0; ni < 4; ++ni) {
                const int r = wc * 64 + ni * 16 + ln;
                bfr[ni] = ld_bf16x8(&Bs[r * 64 + (((kk * 4 + quad) ^ (ln & 7)) * 8)]);
            }
#pragma unroll
            for (int mi = 0; mi < 4; ++mi)
#pragma unroll
                for (int ni = 0; ni < 4; ++ni)
                    acc[mi][ni] = __builtin_amdgcn_mfma_f32_16x16x32_bf16(
                        af[mi], bfr[ni], acc[mi][ni], 0, 0, 0);
        }
    }

#pragma unroll
    for (int ni = 0; ni < 4; ++ni) {
        const int n_local = n_base + wc * 64 + ni * 16 + ln;   // 0..1023
        const float bv_ = bias[n_local];
        const int h = n_local >> 6, d = n_local & 63;
#pragma unroll
        for (int mi = 0; mi < 4; ++mi) {
            const int m0 = m_base + wr * 64 + mi * 16 + quad * 4;
            const int b  = m0 >> 11;
            const int t0 = m0 & (T_ - 1);
            f32x4 v = acc[mi][ni];
            if (which == 2) {
                // permuted [B,H,D,T]: within each 128-kv block,
                // pos(kv) = (kvt>>1)*32 + quad*8 + (kvt&1)*4 + j, kvt=kv>>4
                const int tb   = t0 & ~127;
                const int w128 = t0 & 127;
                const int kvt  = w128 >> 4;
                const int qd   = (w128 >> 2) & 3;
                const int pos  = (kvt >> 1) * 32 + qd * 8 + (kvt & 1) * 4;
                u16x4 pk = { f2bf(v.x + bv_), f2bf(v.y + bv_),
                             f2bf(v.z + bv_), f2bf(v.w + bv_) };
                *(u16x4*)(&vo[((size_t)(b * H_ + h) * D_ + d) * T_ + tb + pos]) = pk;
            } else if (which == 0) {
                unsigned short* dst =
                    qo + ((size_t)(b * H_ + h) * T_ + t0) * (size_t)D_ + d;
                dst[0 * D_] = f2bf((v.x + bv_) * K1_);
                dst[1 * D_] = f2bf((v.y + bv_) * K1_);
                dst[2 * D_] = f2bf((v.z + bv_) * K1_);
                dst[3 * D_] = f2bf((v.w + bv_) * K1_);
            } else {
                unsigned short* dst =
                    ko + ((size_t)(b * H_ + h) * T_ + t0) * (size_t)D_ + d;
                dst[0 * D_] = f2bf(v.x + bv_);
                dst[1 * D_] = f2bf(v.y + bv_);
                dst[2 * D_] = f2bf(v.z + bv_);
                dst[3 * D_] = f2bf(v.w + bv_);
            }
        }
    }
}

// ============================================================
// Kernel 2: flash attention, S^T form. 128 q-rows/block, 32 q/wave
// (2 subtiles sharing every K/V fragment load -> LDS traffic per q halved).
// Ks [128][64] swizzled; Vs [64][128] permuted AND swizzled
// (Vs[d][c] = src[d][c^(d&7)]) -> all frag reads <=2-way (free).
// ============================================================
__global__ __launch_bounds__(256)
void flash_attn(const unsigned short* __restrict__ qb,
                const unsigned short* __restrict__ kb,
                const unsigned short* __restrict__ vtb,
                float* __restrict__ out)
{
    __shared__ alignas(16) unsigned char smem[36864];        // max(32K, Os 36.9K)
    unsigned short* Ks = (unsigned short*)smem;              // [128][64] swz
    unsigned short* Vs = (unsigned short*)(smem + 16384);    // [64][128] perm+swz
    float* Os = (float*)smem;                                // [128][72] epilogue

    const int tid = threadIdx.x;
    const int qt  = blockIdx.x;   // 0..15 (128 q rows each)
    const int bh  = blockIdx.y;   // 0..63
    const int b   = bh >> 4, h = bh & 15;

    const int w = tid >> 6, lane = tid & 63;
    const int ln = lane & 15, quad = lane >> 4;

    const unsigned short* Qb = qb  + (size_t)bh * T_ * D_;
    const unsigned short* Kb = kb  + (size_t)bh * T_ * D_;
    const unsigned short* Vb = vtb + (size_t)bh * D_ * T_;

    // Q (pre-scaled) as B-operand fragments, 2 subtiles
    const int qrow0 = qt * 128 + w * 16 + ln;
    const bf16x8 qA0 = ld_bf16x8(&Qb[(size_t)qrow0 * D_ + quad * 8]);
    const bf16x8 qA1 = ld_bf16x8(&Qb[(size_t)qrow0 * D_ + 32 + quad * 8]);
    const bf16x8 qB0 = ld_bf16x8(&Qb[(size_t)(qrow0 + 64) * D_ + quad * 8]);
    const bf16x8 qB1 = ld_bf16x8(&Qb[(size_t)(qrow0 + 64) * D_ + 32 + quad * 8]);

    // K staging: instr i -> 8 rows of 128B, swizzled chunks
    const int srow   = lane >> 3;
    const int schunk = (lane & 7) ^ srow;
    const int scu    = schunk * 8;
    // V staging: instr i -> 4 rows of 256B; source chunk swizzled so that
    // LDS chunk c holds src chunk c^(d&7)
    const int vrow = lane >> 4;          // 0..3

    const f32x4 fz = {0.f, 0.f, 0.f, 0.f};
    float m2a = -3.0e38f, lia = 0.f;
    float m2b = -3.0e38f, lib = 0.f;
    f32x4 accA[4], accB[4];
#pragma unroll
    for (int dt = 0; dt < 4; ++dt) { accA[dt] = fz; accB[dt] = fz; }

    for (int kv0 = 0; kv0 < T_; kv0 += 128) {
        __syncthreads();
#pragma unroll
        for (int i = 0; i < 4; ++i) {
            const int kr = kv0 + w * 32 + i * 8 + srow;
            gl_lds16(Kb + (size_t)kr * D_ + scu, Ks + (w * 4 + i) * 512);
            const int dr = (w * 4 + i) * 4 + vrow;
            const int vcs = (lane & 15) ^ ((i & 1) * 4 + vrow);   // src chunk
            gl_lds16(Vb + (size_t)dr * T_ + kv0 + vcs * 8, Vs + (w * 4 + i) * 512);
        }
        __syncthreads();

        // S^T = K · Q^T for both subtiles, sharing K fragments
        f32x4 sA[8], sB[8];
#pragma unroll
        for (int kvt = 0; kvt < 8; ++kvt) {
            const int r_ = kvt * 16 + ln;               // r_&7 == ln&7
            bf16x8 kf0 = ld_bf16x8(&Ks[r_ * 64 + ((quad)     ^ (ln & 7)) * 8]);
            bf16x8 kf1 = ld_bf16x8(&Ks[r_ * 64 + ((quad + 4) ^ (ln & 7)) * 8]);
            f32x4 cA = fz, cB = fz;
            cA = __builtin_amdgcn_mfma_f32_16x16x32_bf16(kf0, qA0, cA, 0, 0, 0);
            cB = __builtin_amdgcn_mfma_f32_16x16x32_bf16(kf0, qB0, cB, 0, 0, 0);
            cA = __builtin_amdgcn_mfma_f32_16x16x32_bf16(kf1, qA1, cA, 0, 0, 0);
            cB = __builtin_amdgcn_mfma_f32_16x16x32_bf16(kf1, qB1, cB, 0, 0, 0);
            sA[kvt] = cA; sB[kvt] = cB;
        }

        // online softmax (log2 domain), subtile A
        s16x4 pkA[8], pkB[8];
        float alA, alB;
        {
            f32x4 mm = vmax4(vmax4(vmax4(sA[0], sA[1]), vmax4(sA[2], sA[3])),
                             vmax4(vmax4(sA[4], sA[5]), vmax4(sA[6], sA[7])));
            float mx = fmaxf(fmaxf(mm.x, mm.y), fmaxf(mm.z, mm.w));
            mx = fmaxf(mx, __shfl_xor(mx, 16));
            mx = fmaxf(mx, __shfl_xor(mx, 32));
            const float nm = fmaxf(m2a, mx);
            alA = __builtin_amdgcn_exp2f(m2a - nm);
            m2a = nm;
            f32x4 rsv = fz;
#pragma unroll
            for (int kvt = 0; kvt < 8; ++kvt) {
                f32x4 pv;
                pv.x = __builtin_amdgcn_exp2f(sA[kvt].x - m2a);
                pv.y = __builtin_amdgcn_exp2f(sA[kvt].y - m2a);
                pv.z = __builtin_amdgcn_exp2f(sA[kvt].z - m2a);
                pv.w = __builtin_amdgcn_exp2f(sA[kvt].w - m2a);
                rsv += pv;
                u32x2 pd = { pack2bf(pv.x, pv.y), pack2bf(pv.z, pv.w) };
                pkA[kvt] = __builtin_bit_cast(s16x4, pd);
            }
            float rs = (rsv.x + rsv.y) + (rsv.z + rsv.w);
            rs += __shfl_xor(rs, 16);
            rs += __shfl_xor(rs, 32);
            lia = lia * alA + rs;
        }
        // subtile B
        {
            f32x4 mm = vmax4(vmax4(vmax4(sB[0], sB[1]), vmax4(sB[2], sB[3])),
                             vmax4(vmax4(sB[4], sB[5]), vmax4(sB[6], sB[7])));
            float mx = fmaxf(fmaxf(mm.x, mm.y), fmaxf(mm.z, mm.w));
            mx = fmaxf(mx, __shfl_xor(mx, 16));
            mx = fmaxf(mx, __shfl_xor(mx, 32));
            const float nm = fmaxf(m2b, mx);
            alB = __builtin_amdgcn_exp2f(m2b - nm);
            m2b = nm;
            f32x4 rsv = fz;
#pragma unroll
            for (int kvt = 0; kvt < 8; ++kvt) {
                f32x4 pv;
                pv.x = __builtin_amdgcn_exp2f(sB[kvt].x - m2b);
                pv.y = __builtin_amdgcn_exp2f(sB[kvt].y - m2b);
                pv.z = __builtin_amdgcn_exp2f(sB[kvt].z - m2b);
                pv.w = __builtin_amdgcn_exp2f(sB[kvt].w - m2b);
                rsv += pv;
                u32x2 pd = { pack2bf(pv.x, pv.y), pack2bf(pv.z, pv.w) };
                pkB[kvt] = __builtin_bit_cast(s16x4, pd);
            }
            float rs = (rsv.x + rsv.y) + (rsv.z + rsv.w);
            rs += __shfl_xor(rs, 16);
            rs += __shfl_xor(rs, 32);
            lib = lib * alB + rs;
        }

#pragma unroll
        for (int dt = 0; dt < 4; ++dt) { accA[dt] *= alA; accB[dt] *= alB; }

        // O^T += V^T · P^T, sharing V fragments between subtiles
#pragma unroll
        for (int dt = 0; dt < 4; ++dt) {
            const int vr = dt * 16 + ln;
#pragma unroll
            for (int p = 0; p < 4; ++p) {
                const int cl = ((p * 4 + quad) ^ (ln & 7));
                u16x8 vv = *(const u16x8*)(&Vs[vr * 128 + cl * 8]);
                s16x4 v0 = { (short)vv[0], (short)vv[1], (short)vv[2], (short)vv[3] };
                s16x4 v1 = { (short)vv[4], (short)vv[5], (short)vv[6], (short)vv[7] };
                accA[dt] = mfma16(v0, pkA[2 * p],     accA[dt]);
                accB[dt] = mfma16(v0, pkB[2 * p],     accB[dt]);
                accA[dt] = mfma16(v1, pkA[2 * p + 1], accA[dt]);
                accB[dt] = mfma16(v1, pkB[2 * p + 1], accB[dt]);
            }
        }
    }

    // epilogue: normalize, transpose O^T -> O via LDS ([128][72] f32)
    __syncthreads();
    const float rva = 1.0f / lia, rvb = 1.0f / lib;
#pragma unroll
    for (int dt = 0; dt < 4; ++dt)
#pragma unroll
        for (int r = 0; r < 4; ++r) {
            Os[(w * 16 + ln) * 72 + dt * 16 + quad * 4 + r]        = accA[dt][r] * rva;
            Os[(64 + w * 16 + ln) * 72 + dt * 16 + quad * 4 + r]   = accB[dt][r] * rvb;
        }
    __syncthreads();

    const int q  = tid >> 1;              // 0..127
    const int c0 = (tid & 1) * 32;
    const float* src = &Os[q * 72 + c0];
    float* dst = &out[((size_t)(b * T_ + qt * 128 + q)) * C_ + h * 64 + c0];
#pragma unroll
    for (int i = 0; i < 8; ++i)
        *(f32x4*)(dst + i * 4) = *(const f32x4*)(src + i * 4);
}

// ============================================================
extern "C" void kernel_launch(void* const* d_in, const int* in_sizes, int n_in,
                              void* d_out, int out_size, void* d_ws, size_t ws_size,
                              hipStream_t stream) {
    const float* q_x = (const float*)d_in[0];
    const float* Wq  = (const float*)d_in[1];
    const float* bq  = (const float*)d_in[2];
    const float* Wk  = (const float*)d_in[3];
    const float* bk  = (const float*)d_in[4];
    const float* Wv  = (const float*)d_in[5];
    const float* bv  = (const float*)d_in[6];
    float* out = (float*)d_out;

    const size_t elems = (size_t)M_ * C_;      // 8,388,608
    unsigned short* xb  = (unsigned short*)d_ws;
    unsigned short* wb  = xb + elems;                    // 3*C*C
    unsigned short* qb  = wb + (size_t)3 * C_ * C_;
    unsigned short* kb  = qb + elems;
    unsigned short* vtb = kb + elems;
    (void)ws_size; (void)in_sizes; (void)n_in; (void)out_size;

    const int64_t total4 = X4_ + 3 * W4_;      // 2,883,584
    cvt_bf16<<<(int)(total4 / 256), 256, 0, stream>>>(q_x, Wq, Wk, Wv, xb, wb);

    qkv_gemm<<<dim3(M_ / 128, 24), 256, 0, stream>>>(
        xb, wb, bq, bk, bv, qb, kb, vtb);

    flash_attn<<<dim3(T_ / 128, B_ * H_), 256, 0, stream>>>(qb, kb, vtb, out);
}

// Round 6
// 287.801 us; speedup vs baseline: 1.1300x; 1.0175x over previous
//
#include <hip/hip_runtime.h>
#include <hip/hip_bf16.h>
#include <stdint.h>
#include <stddef.h>

// ---------------- problem constants ----------------
#define B_ 4
#define T_ 2048
#define C_ 1024
#define H_ 16
#define D_ 64
#define M_ (B_ * T_)   // 8192 rows of x

typedef __bf16 bf16x8 __attribute__((ext_vector_type(8)));
typedef float  f32x4  __attribute__((ext_vector_type(4)));
typedef short  s16x4  __attribute__((ext_vector_type(4)));
typedef unsigned short u16x8 __attribute__((ext_vector_type(8)));
typedef unsigned short u16x4 __attribute__((ext_vector_type(4)));
typedef unsigned int   u32x2 __attribute__((ext_vector_type(2)));

__device__ __forceinline__ unsigned short f2bf(float f) {
    union { float f; unsigned int u; } c; c.f = f;
    unsigned int u = c.u;
    unsigned int r = (u + 0x7fffu + ((u >> 16) & 1u)) >> 16;
    return (unsigned short)r;
}

// pack two f32 -> one dword of 2 bf16 (round-half-up; <=1ulp vs RNE).
__device__ __forceinline__ unsigned int pack2bf(float a, float b) {
    unsigned int ua = __builtin_bit_cast(unsigned int, a) + 0x8000u;
    unsigned int ub = __builtin_bit_cast(unsigned int, b) + 0x8000u;
    return __builtin_amdgcn_perm(ub, ua, 0x07060302u);
}

__device__ __forceinline__ bf16x8 ld_bf16x8(const unsigned short* p) {
    u16x8 v = *(const u16x8*)p;
    return __builtin_bit_cast(bf16x8, v);
}

// async global -> LDS, 16 B per lane (dest = uniform base + lane*16)
__device__ __forceinline__ void gl_lds16(const unsigned short* g, unsigned short* l) {
    __builtin_amdgcn_global_load_lds(
        (const void __attribute__((address_space(1)))*)g,
        (void __attribute__((address_space(3)))*)l, 16, 0, 0);
}

__device__ __forceinline__ f32x4 mfma16(s16x4 a, s16x4 b, f32x4 c) {
#if __has_builtin(__builtin_amdgcn_mfma_f32_16x16x16bf16_1k)
    return __builtin_amdgcn_mfma_f32_16x16x16bf16_1k(a, b, c, 0, 0, 0);
#else
    asm volatile("v_mfma_f32_16x16x16_bf16 %0, %1, %2, %0"
                 : "+v"(c) : "v"(a), "v"(b));
    return c;
#endif
}

__device__ __forceinline__ f32x4 vmax4(f32x4 a, f32x4 b) {
    f32x4 r;
    r.x = fmaxf(a.x, b.x); r.y = fmaxf(a.y, b.y);
    r.z = fmaxf(a.z, b.z); r.w = fmaxf(a.w, b.w);
    return r;
}

// ============================================================
// Kernel 0: fp32 -> bf16 conversion of x and {Wq,Wk,Wv} (concat).
// ============================================================
#define X4_ ((int64_t)M_ * C_ / 4)   // 2,097,152 float4s
#define W4_ ((int64_t)C_ * C_ / 4)   //   262,144 float4s per W

__global__ __launch_bounds__(256)
void cvt_bf16(const float* __restrict__ x,
              const float* __restrict__ Wq, const float* __restrict__ Wk,
              const float* __restrict__ Wv,
              unsigned short* __restrict__ xb, unsigned short* __restrict__ wb)
{
    const int64_t i4 = (int64_t)blockIdx.x * blockDim.x + threadIdx.x;
    const float* src; unsigned short* dst; int64_t off;
    if (i4 < X4_) { src = x; dst = xb; off = i4; }
    else {
        int64_t j = i4 - X4_;
        int which = (int)(j / W4_);
        off = j - (int64_t)which * W4_;
        src = (which == 0) ? Wq : (which == 1) ? Wk : Wv;
        dst = wb + (int64_t)which * C_ * C_;
    }
    f32x4 v = *(const f32x4*)(src + off * 4);
    u16x4 o = { f2bf(v.x), f2bf(v.y), f2bf(v.z), f2bf(v.w) };
    *(u16x4*)(dst + off * 4) = o;
}

// ============================================================
// Kernel 1: y = xb @ Wb^T + b, N concat = 3072. Pure bf16.
// BK=64, XOR-chunk-swizzled LDS ([128][64] u16, LDS[r][c]=src[r][c^(r&7)]).
// q stored PRE-SCALED by 0.125*log2(e); v stored [B,H,D,T] with a
// 128-kv-block internal permutation matching flash_attn's PV A-frags.
// ============================================================
#define K1_ 0.180336880f   // 0.125 * log2(e)

__global__ __launch_bounds__(256)
void qkv_gemm(const unsigned short* __restrict__ xb,
              const unsigned short* __restrict__ wb,
              const float* __restrict__ bq, const float* __restrict__ bk,
              const float* __restrict__ bv,
              unsigned short* __restrict__ qo,
              unsigned short* __restrict__ ko,
              unsigned short* __restrict__ vo)
{
    __shared__ alignas(16) unsigned short As[128 * 64];
    __shared__ alignas(16) unsigned short Bs[128 * 64];

    const int tid   = threadIdx.x;
    const int bm    = blockIdx.x;          // 0..63
    const int bn    = blockIdx.y;          // 0..23
    const int which = bn >> 3;             // 0=q 1=k 2=v
    const int n_base = (bn & 7) * 128;
    const int nrow   = bn * 128;
    const int m_base = bm * 128;

    const float* bias = (which == 0) ? bq : (which == 1) ? bk : bv;

    const int w = tid >> 6, lane = tid & 63;
    const int wr = w >> 1, wc = w & 1;
    const int ln = lane & 15, quad = lane >> 4;

    const int srow   = lane >> 3;                  // 0..7
    const int schunk = (lane & 7) ^ srow;          // 0..7
    const int scu    = schunk * 8;

    const f32x4 fz = {0.f, 0.f, 0.f, 0.f};
    f32x4 acc[4][4];
#pragma unroll
    for (int i = 0; i < 4; ++i)
#pragma unroll
        for (int j = 0; j < 4; ++j) acc[i][j] = fz;

    for (int k0 = 0; k0 < C_; k0 += 64) {
        __syncthreads();
#pragma unroll
        for (int i = 0; i < 4; ++i) {
            const int r = w * 32 + i * 8 + srow;
            gl_lds16(xb + (size_t)(m_base + r) * C_ + k0 + scu, As + (w * 4 + i) * 512);
            gl_lds16(wb + (size_t)(nrow  + r) * C_ + k0 + scu, Bs + (w * 4 + i) * 512);
        }
        __syncthreads();

#pragma unroll
        for (int kk = 0; kk < 2; ++kk) {
            bf16x8 af[4], bfr[4];
#pragma unroll
            for (int mi = 0; mi < 4; ++mi) {
                const int r = wr * 64 + mi * 16 + ln;
                af[mi] = ld_bf16x8(&As[r * 64 + (((kk * 4 + quad) ^ (ln & 7)) * 8)]);
            }
#pragma unroll
            for (int ni = 0; ni < 4; ++ni) {
                const int r = wc * 64 + ni * 16 + ln;
                bfr[ni] = ld_bf16x8(&Bs[r * 64 + (((kk * 4 + quad) ^ (ln & 7)) * 8)]);
            }
#pragma unroll
            for (int mi = 0; mi < 4; ++mi)
#pragma unroll
                for (int ni = 0; ni < 4; ++ni)
                    acc[mi][ni] = __builtin_amdgcn_mfma_f32_16x16x32_bf16(
                        af[mi], bfr[ni], acc[mi][ni], 0, 0, 0);
        }
    }

#pragma unroll
    for (int ni = 0; ni < 4; ++ni) {
        const int n_local = n_base + wc * 64 + ni * 16 + ln;   // 0..1023
        const float bv_ = bias[n_local];
        const int h = n_local >> 6, d = n_local & 63;
#pragma unroll
        for (int mi = 0; mi < 4; ++mi) {
            const int m0 = m_base + wr * 64 + mi * 16 + quad * 4;
            const int b  = m0 >> 11;
            const int t0 = m0 & (T_ - 1);
            f32x4 v = acc[mi][ni];
            if (which == 2) {
                // permuted [B,H,D,T]: within each 128-kv block,
                // pos(kv) = (kvt>>1)*32 + quad*8 + (kvt&1)*4 + j, kvt=kv>>4
                const int tb   = t0 & ~127;
                const int w128 = t0 & 127;
                const int kvt  = w128 >> 4;
                const int qd   = (w128 >> 2) & 3;
                const int pos  = (kvt >> 1) * 32 + qd * 8 + (kvt & 1) * 4;
                u16x4 pk = { f2bf(v.x + bv_), f2bf(v.y + bv_),
                             f2bf(v.z + bv_), f2bf(v.w + bv_) };
                *(u16x4*)(&vo[((size_t)(b * H_ + h) * D_ + d) * T_ + tb + pos]) = pk;
            } else if (which == 0) {
                unsigned short* dst =
                    qo + ((size_t)(b * H_ + h) * T_ + t0) * (size_t)D_ + d;
                dst[0 * D_] = f2bf((v.x + bv_) * K1_);
                dst[1 * D_] = f2bf((v.y + bv_) * K1_);
                dst[2 * D_] = f2bf((v.z + bv_) * K1_);
                dst[3 * D_] = f2bf((v.w + bv_) * K1_);
            } else {
                unsigned short* dst =
                    ko + ((size_t)(b * H_ + h) * T_ + t0) * (size_t)D_ + d;
                dst[0 * D_] = f2bf(v.x + bv_);
                dst[1 * D_] = f2bf(v.y + bv_);
                dst[2 * D_] = f2bf(v.z + bv_);
                dst[3 * D_] = f2bf(v.w + bv_);
            }
        }
    }
}

// ============================================================
// Kernel 2: flash attention, S^T form, 128 q/block (2 subtiles/wave),
// DOUBLE-BUFFERED K/V staging: prefetch for iter k+1 is issued right
// after the barrier that publishes iter k, so the compiler's
// vmcnt(0)-drain at the NEXT barrier gives it a full compute phase
// (~1200 cyc > 900 cyc HBM latency) to land.
// Ks [128][64] swz; Vs [64][128] perm+swz; all frag reads <=2-way.
// ============================================================
__global__ __launch_bounds__(256)
void flash_attn(const unsigned short* __restrict__ qb,
                const unsigned short* __restrict__ kb,
                const unsigned short* __restrict__ vtb,
                float* __restrict__ out)
{
    __shared__ alignas(16) unsigned char smem[65536];   // 2 x (Ks 16K + Vs 16K)
    float* Os = (float*)smem;                           // [128][72] epilogue overlay

    const int tid = threadIdx.x;
    const int qt  = blockIdx.x;   // 0..15 (128 q rows each)
    const int bh  = blockIdx.y;   // 0..63
    const int b   = bh >> 4, h = bh & 15;

    const int w = tid >> 6, lane = tid & 63;
    const int ln = lane & 15, quad = lane >> 4;

    const unsigned short* Qb = qb  + (size_t)bh * T_ * D_;
    const unsigned short* Kb = kb  + (size_t)bh * T_ * D_;
    const unsigned short* Vb = vtb + (size_t)bh * D_ * T_;

    // Q (pre-scaled) as B-operand fragments, 2 subtiles
    const int qrow0 = qt * 128 + w * 16 + ln;
    const bf16x8 qA0 = ld_bf16x8(&Qb[(size_t)qrow0 * D_ + quad * 8]);
    const bf16x8 qA1 = ld_bf16x8(&Qb[(size_t)qrow0 * D_ + 32 + quad * 8]);
    const bf16x8 qB0 = ld_bf16x8(&Qb[(size_t)(qrow0 + 64) * D_ + quad * 8]);
    const bf16x8 qB1 = ld_bf16x8(&Qb[(size_t)(qrow0 + 64) * D_ + 32 + quad * 8]);

    // K staging: instr i -> 8 rows of 128B, swizzled chunks
    const int srow   = lane >> 3;
    const int schunk = (lane & 7) ^ srow;
    const int scu    = schunk * 8;
    // V staging: instr i -> 4 rows of 256B; source chunk swizzled
    const int vrow = lane >> 4;          // 0..3

    const f32x4 fz = {0.f, 0.f, 0.f, 0.f};
    float m2a = -3.0e38f, lia = 0.f;
    float m2b = -3.0e38f, lib = 0.f;
    f32x4 accA[4], accB[4];
#pragma unroll
    for (int dt = 0; dt < 4; ++dt) { accA[dt] = fz; accB[dt] = fz; }

    // ---- staging helper (issues 8 gl_lds for one kv tile into buf) ----
    auto stage = [&](int kv0, int buf) {
        unsigned short* Ks = (unsigned short*)(smem + buf * 32768);
        unsigned short* Vs = (unsigned short*)(smem + buf * 32768 + 16384);
#pragma unroll
        for (int i = 0; i < 4; ++i) {
            const int kr = kv0 + w * 32 + i * 8 + srow;
            gl_lds16(Kb + (size_t)kr * D_ + scu, Ks + (w * 4 + i) * 512);
            const int dr = (w * 4 + i) * 4 + vrow;
            const int vcs = (lane & 15) ^ ((i & 1) * 4 + vrow);   // src chunk
            gl_lds16(Vb + (size_t)dr * T_ + kv0 + vcs * 8, Vs + (w * 4 + i) * 512);
        }
    };

    stage(0, 0);   // preload tile 0

    for (int kv0 = 0; kv0 < T_; kv0 += 128) {
        const int cur = (kv0 >> 7) & 1;
        // barrier: (a) vmcnt(0)-drain publishes staging for THIS tile,
        // (b) all waves done reading buf cur^1 from the previous iter.
        __syncthreads();
        if (kv0 + 128 < T_) stage(kv0 + 128, cur ^ 1);   // prefetch next

        const unsigned short* Ks = (const unsigned short*)(smem + cur * 32768);
        const unsigned short* Vs = (const unsigned short*)(smem + cur * 32768 + 16384);

        // S^T = K · Q^T for both subtiles, sharing K fragments
        f32x4 sA[8], sB[8];
#pragma unroll
        for (int kvt = 0; kvt < 8; ++kvt) {
            const int r_ = kvt * 16 + ln;               // r_&7 == ln&7
            bf16x8 kf0 = ld_bf16x8(&Ks[r_ * 64 + ((quad)     ^ (ln & 7)) * 8]);
            bf16x8 kf1 = ld_bf16x8(&Ks[r_ * 64 + ((quad + 4) ^ (ln & 7)) * 8]);
            f32x4 cA = fz, cB = fz;
            cA = __builtin_amdgcn_mfma_f32_16x16x32_bf16(kf0, qA0, cA, 0, 0, 0);
            cB = __builtin_amdgcn_mfma_f32_16x16x32_bf16(kf0, qB0, cB, 0, 0, 0);
            cA = __builtin_amdgcn_mfma_f32_16x16x32_bf16(kf1, qA1, cA, 0, 0, 0);
            cB = __builtin_amdgcn_mfma_f32_16x16x32_bf16(kf1, qB1, cB, 0, 0, 0);
            sA[kvt] = cA; sB[kvt] = cB;
        }

        // online softmax (log2 domain), subtile A
        s16x4 pkA[8], pkB[8];
        float alA, alB;
        {
            f32x4 mm = vmax4(vmax4(vmax4(sA[0], sA[1]), vmax4(sA[2], sA[3])),
                             vmax4(vmax4(sA[4], sA[5]), vmax4(sA[6], sA[7])));
            float mx = fmaxf(fmaxf(mm.x, mm.y), fmaxf(mm.z, mm.w));
            mx = fmaxf(mx, __shfl_xor(mx, 16));
            mx = fmaxf(mx, __shfl_xor(mx, 32));
            const float nm = fmaxf(m2a, mx);
            alA = __builtin_amdgcn_exp2f(m2a - nm);
            m2a = nm;
            f32x4 rsv = fz;
#pragma unroll
            for (int kvt = 0; kvt < 8; ++kvt) {
                f32x4 pv;
                pv.x = __builtin_amdgcn_exp2f(sA[kvt].x - m2a);
                pv.y = __builtin_amdgcn_exp2f(sA[kvt].y - m2a);
                pv.z = __builtin_amdgcn_exp2f(sA[kvt].z - m2a);
                pv.w = __builtin_amdgcn_exp2f(sA[kvt].w - m2a);
                rsv += pv;
                u32x2 pd = { pack2bf(pv.x, pv.y), pack2bf(pv.z, pv.w) };
                pkA[kvt] = __builtin_bit_cast(s16x4, pd);
            }
            float rs = (rsv.x + rsv.y) + (rsv.z + rsv.w);
            rs += __shfl_xor(rs, 16);
            rs += __shfl_xor(rs, 32);
            lia = lia * alA + rs;
        }
        // subtile B
        {
            f32x4 mm = vmax4(vmax4(vmax4(sB[0], sB[1]), vmax4(sB[2], sB[3])),
                             vmax4(vmax4(sB[4], sB[5]), vmax4(sB[6], sB[7])));
            float mx = fmaxf(fmaxf(mm.x, mm.y), fmaxf(mm.z, mm.w));
            mx = fmaxf(mx, __shfl_xor(mx, 16));
            mx = fmaxf(mx, __shfl_xor(mx, 32));
            const float nm = fmaxf(m2b, mx);
            alB = __builtin_amdgcn_exp2f(m2b - nm);
            m2b = nm;
            f32x4 rsv = fz;
#pragma unroll
            for (int kvt = 0; kvt < 8; ++kvt) {
                f32x4 pv;
                pv.x = __builtin_amdgcn_exp2f(sB[kvt].x - m2b);
                pv.y = __builtin_amdgcn_exp2f(sB[kvt].y - m2b);
                pv.z = __builtin_amdgcn_exp2f(sB[kvt].z - m2b);
                pv.w = __builtin_amdgcn_exp2f(sB[kvt].w - m2b);
                rsv += pv;
                u32x2 pd = { pack2bf(pv.x, pv.y), pack2bf(pv.z, pv.w) };
                pkB[kvt] = __builtin_bit_cast(s16x4, pd);
            }
            float rs = (rsv.x + rsv.y) + (rsv.z + rsv.w);
            rs += __shfl_xor(rs, 16);
            rs += __shfl_xor(rs, 32);
            lib = lib * alB + rs;
        }

#pragma unroll
        for (int dt = 0; dt < 4; ++dt) { accA[dt] *= alA; accB[dt] *= alB; }

        // O^T += V^T · P^T, sharing V fragments between subtiles
#pragma unroll
        for (int dt = 0; dt < 4; ++dt) {
            const int vr = dt * 16 + ln;
#pragma unroll
            for (int p = 0; p < 4; ++p) {
                const int cl = ((p * 4 + quad) ^ (ln & 7));
                u16x8 vv = *(const u16x8*)(&Vs[vr * 128 + cl * 8]);
                s16x4 v0 = { (short)vv[0], (short)vv[1], (short)vv[2], (short)vv[3] };
                s16x4 v1 = { (short)vv[4], (short)vv[5], (short)vv[6], (short)vv[7] };
                accA[dt] = mfma16(v0, pkA[2 * p],     accA[dt]);
                accB[dt] = mfma16(v0, pkB[2 * p],     accB[dt]);
                accA[dt] = mfma16(v1, pkA[2 * p + 1], accA[dt]);
                accB[dt] = mfma16(v1, pkB[2 * p + 1], accB[dt]);
            }
        }
    }

    // epilogue: normalize, transpose O^T -> O via LDS ([128][72] f32)
    __syncthreads();
    const float rva = 1.0f / lia, rvb = 1.0f / lib;
#pragma unroll
    for (int dt = 0; dt < 4; ++dt)
#pragma unroll
        for (int r = 0; r < 4; ++r) {
            Os[(w * 16 + ln) * 72 + dt * 16 + quad * 4 + r]        = accA[dt][r] * rva;
            Os[(64 + w * 16 + ln) * 72 + dt * 16 + quad * 4 + r]   = accB[dt][r] * rvb;
        }
    __syncthreads();

    const int q  = tid >> 1;              // 0..127
    const int c0 = (tid & 1) * 32;
    const float* src = &Os[q * 72 + c0];
    float* dst = &out[((size_t)(b * T_ + qt * 128 + q)) * C_ + h * 64 + c0];
#pragma unroll
    for (int i = 0; i < 8; ++i)
        *(f32x4*)(dst + i * 4) = *(const f32x4*)(src + i * 4);
}

// ============================================================
extern "C" void kernel_launch(void* const* d_in, const int* in_sizes, int n_in,
                              void* d_out, int out_size, void* d_ws, size_t ws_size,
                              hipStream_t stream) {
    const float* q_x = (const float*)d_in[0];
    const float* Wq  = (const float*)d_in[1];
    const float* bq  = (const float*)d_in[2];
    const float* Wk  = (const float*)d_in[3];
    const float* bk  = (const float*)d_in[4];
    const float* Wv  = (const float*)d_in[5];
    const float* bv  = (const float*)d_in[6];
    float* out = (float*)d_out;

    const size_t elems = (size_t)M_ * C_;      // 8,388,608
    unsigned short* xb  = (unsigned short*)d_ws;
    unsigned short* wb  = xb + elems;                    // 3*C*C
    unsigned short* qb  = wb + (size_t)3 * C_ * C_;
    unsigned short* kb  = qb + elems;
    unsigned short* vtb = kb + elems;
    (void)ws_size; (void)in_sizes; (void)n_in; (void)out_size;

    const int64_t total4 = X4_ + 3 * W4_;      // 2,883,584
    cvt_bf16<<<(int)(total4 / 256), 256, 0, stream>>>(q_x, Wq, Wk, Wv, xb, wb);

    qkv_gemm<<<dim3(M_ / 128, 24), 256, 0, stream>>>(
        xb, wb, bq, bk, bv, qb, kb, vtb);

    flash_attn<<<dim3(T_ / 128, B_ * H_), 256, 0, stream>>>(qb, kb, vtb, out);
}

// Round 7
// 281.185 us; speedup vs baseline: 1.1566x; 1.0235x over previous
//
#include <hip/hip_runtime.h>
#include <hip/hip_bf16.h>
#include <stdint.h>
#include <stddef.h>

// ---------------- problem constants ----------------
#define B_ 4
#define T_ 2048
#define C_ 1024
#define H_ 16
#define D_ 64
#define M_ (B_ * T_)   // 8192 rows of x

typedef __bf16 bf16x8 __attribute__((ext_vector_type(8)));
typedef float  f32x4  __attribute__((ext_vector_type(4)));
typedef unsigned short u16x8 __attribute__((ext_vector_type(8)));
typedef unsigned short u16x4 __attribute__((ext_vector_type(4)));
typedef unsigned int   u32x4 __attribute__((ext_vector_type(4)));

__device__ __forceinline__ unsigned short f2bf(float f) {
    union { float f; unsigned int u; } c; c.f = f;
    unsigned int u = c.u;
    unsigned int r = (u + 0x7fffu + ((u >> 16) & 1u)) >> 16;
    return (unsigned short)r;
}

// pack two f32 -> one dword of 2 bf16 (round-half-up; <=1ulp vs RNE).
__device__ __forceinline__ unsigned int pack2bf(float a, float b) {
    unsigned int ua = __builtin_bit_cast(unsigned int, a) + 0x8000u;
    unsigned int ub = __builtin_bit_cast(unsigned int, b) + 0x8000u;
    return __builtin_amdgcn_perm(ub, ua, 0x07060302u);
}

__device__ __forceinline__ bf16x8 ld_bf16x8(const unsigned short* p) {
    u16x8 v = *(const u16x8*)p;
    return __builtin_bit_cast(bf16x8, v);
}

// async global -> LDS, 16 B per lane (dest = uniform base + lane*16)
__device__ __forceinline__ void gl_lds16(const unsigned short* g, unsigned short* l) {
    __builtin_amdgcn_global_load_lds(
        (const void __attribute__((address_space(1)))*)g,
        (void __attribute__((address_space(3)))*)l, 16, 0, 0);
}

__device__ __forceinline__ f32x4 vmax4(f32x4 a, f32x4 b) {
    f32x4 r;
    r.x = fmaxf(a.x, b.x); r.y = fmaxf(a.y, b.y);
    r.z = fmaxf(a.z, b.z); r.w = fmaxf(a.w, b.w);
    return r;
}

// ============================================================
// Kernel 0: fp32 -> bf16 conversion of x and {Wq,Wk,Wv} (concat).
// ============================================================
#define X4_ ((int64_t)M_ * C_ / 4)   // 2,097,152 float4s
#define W4_ ((int64_t)C_ * C_ / 4)   //   262,144 float4s per W

__global__ __launch_bounds__(256)
void cvt_bf16(const float* __restrict__ x,
              const float* __restrict__ Wq, const float* __restrict__ Wk,
              const float* __restrict__ Wv,
              unsigned short* __restrict__ xb, unsigned short* __restrict__ wb)
{
    const int64_t i4 = (int64_t)blockIdx.x * blockDim.x + threadIdx.x;
    const float* src; unsigned short* dst; int64_t off;
    if (i4 < X4_) { src = x; dst = xb; off = i4; }
    else {
        int64_t j = i4 - X4_;
        int which = (int)(j / W4_);
        off = j - (int64_t)which * W4_;
        src = (which == 0) ? Wq : (which == 1) ? Wk : Wv;
        dst = wb + (int64_t)which * C_ * C_;
    }
    f32x4 v = *(const f32x4*)(src + off * 4);
    u16x4 o = { f2bf(v.x), f2bf(v.y), f2bf(v.z), f2bf(v.w) };
    *(u16x4*)(dst + off * 4) = o;
}

// ============================================================
// Kernel 1: y = xb @ Wb^T + b, N concat = 3072. Pure bf16.
// BK=64, XOR-chunk-swizzled LDS ([128][64] u16, LDS[r][c]=src[r][c^(r&7)]).
// q stored PRE-SCALED by 0.125*log2(e); v stored [B,H,D,T] with a
// 128-kv-block internal permutation matching flash_attn's PV A-frags.
// ============================================================
#define K1_ 0.180336880f   // 0.125 * log2(e)

__global__ __launch_bounds__(256)
void qkv_gemm(const unsigned short* __restrict__ xb,
              const unsigned short* __restrict__ wb,
              const float* __restrict__ bq, const float* __restrict__ bk,
              const float* __restrict__ bv,
              unsigned short* __restrict__ qo,
              unsigned short* __restrict__ ko,
              unsigned short* __restrict__ vo)
{
    __shared__ alignas(16) unsigned short As[128 * 64];
    __shared__ alignas(16) unsigned short Bs[128 * 64];

    const int tid   = threadIdx.x;
    const int bm    = blockIdx.x;          // 0..63
    const int bn    = blockIdx.y;          // 0..23
    const int which = bn >> 3;             // 0=q 1=k 2=v
    const int n_base = (bn & 7) * 128;
    const int nrow   = bn * 128;
    const int m_base = bm * 128;

    const float* bias = (which == 0) ? bq : (which == 1) ? bk : bv;

    const int w = tid >> 6, lane = tid & 63;
    const int wr = w >> 1, wc = w & 1;
    const int ln = lane & 15, quad = lane >> 4;

    const int srow   = lane >> 3;                  // 0..7
    const int schunk = (lane & 7) ^ srow;          // 0..7
    const int scu    = schunk * 8;

    const f32x4 fz = {0.f, 0.f, 0.f, 0.f};
    f32x4 acc[4][4];
#pragma unroll
    for (int i = 0; i < 4; ++i)
#pragma unroll
        for (int j = 0; j < 4; ++j) acc[i][j] = fz;

    for (int k0 = 0; k0 < C_; k0 += 64) {
        __syncthreads();
#pragma unroll
        for (int i = 0; i < 4; ++i) {
            const int r = w * 32 + i * 8 + srow;
            gl_lds16(xb + (size_t)(m_base + r) * C_ + k0 + scu, As + (w * 4 + i) * 512);
            gl_lds16(wb + (size_t)(nrow  + r) * C_ + k0 + scu, Bs + (w * 4 + i) * 512);
        }
        __syncthreads();

#pragma unroll
        for (int kk = 0; kk < 2; ++kk) {
            bf16x8 af[4], bfr[4];
#pragma unroll
            for (int mi = 0; mi < 4; ++mi) {
                const int r = wr * 64 + mi * 16 + ln;
                af[mi] = ld_bf16x8(&As[r * 64 + (((kk * 4 + quad) ^ (ln & 7)) * 8)]);
            }
#pragma unroll
            for (int ni = 0; ni < 4; ++ni) {
                const int r = wc * 64 + ni * 16 + ln;
                bfr[ni] = ld_bf16x8(&Bs[r * 64 + (((kk * 4 + quad) ^ (ln & 7)) * 8)]);
            }
#pragma unroll
            for (int mi = 0; mi < 4; ++mi)
#pragma unroll
                for (int ni = 0; ni < 4; ++ni)
                    acc[mi][ni] = __builtin_amdgcn_mfma_f32_16x16x32_bf16(
                        af[mi], bfr[ni], acc[mi][ni], 0, 0, 0);
        }
    }

#pragma unroll
    for (int ni = 0; ni < 4; ++ni) {
        const int n_local = n_base + wc * 64 + ni * 16 + ln;   // 0..1023
        const float bv_ = bias[n_local];
        const int h = n_local >> 6, d = n_local & 63;
#pragma unroll
        for (int mi = 0; mi < 4; ++mi) {
            const int m0 = m_base + wr * 64 + mi * 16 + quad * 4;
            const int b  = m0 >> 11;
            const int t0 = m0 & (T_ - 1);
            f32x4 v = acc[mi][ni];
            if (which == 2) {
                // permuted [B,H,D,T]: within each 128-kv block,
                // pos(kv) = (kvt>>1)*32 + qd*8 + (kvt&1)*4 + j, kvt=kv>>4
                const int tb   = t0 & ~127;
                const int w128 = t0 & 127;
                const int kvt  = w128 >> 4;
                const int qd   = (w128 >> 2) & 3;
                const int pos  = (kvt >> 1) * 32 + qd * 8 + (kvt & 1) * 4;
                u16x4 pk = { f2bf(v.x + bv_), f2bf(v.y + bv_),
                             f2bf(v.z + bv_), f2bf(v.w + bv_) };
                *(u16x4*)(&vo[((size_t)(b * H_ + h) * D_ + d) * T_ + tb + pos]) = pk;
            } else if (which == 0) {
                unsigned short* dst =
                    qo + ((size_t)(b * H_ + h) * T_ + t0) * (size_t)D_ + d;
                dst[0 * D_] = f2bf((v.x + bv_) * K1_);
                dst[1 * D_] = f2bf((v.y + bv_) * K1_);
                dst[2 * D_] = f2bf((v.z + bv_) * K1_);
                dst[3 * D_] = f2bf((v.w + bv_) * K1_);
            } else {
                unsigned short* dst =
                    ko + ((size_t)(b * H_ + h) * T_ + t0) * (size_t)D_ + d;
                dst[0 * D_] = f2bf(v.x + bv_);
                dst[1 * D_] = f2bf(v.y + bv_);
                dst[2 * D_] = f2bf(v.z + bv_);
                dst[3 * D_] = f2bf(v.w + bv_);
            }
        }
    }
}

// ============================================================
// Kernel 2: flash attention, S^T form, 128 q/block (2 subtiles/wave).
// PV now uses mfma_f32_16x16x32_bf16 directly: the stored V permutation
// IS the 16x16x32 A-layout for k-order kv = p*32+(j<4 ? 4q+j : 16+4q+j-4),
// and the B operand for that k-order is exactly concat(pk[2p],pk[2p+1])
// -- the pks dwords as packed in the exp loop. Zero operand-massage VALU.
// LDS 48K: K double-buffered (prefetch spans full iter), V single-buffered
// (staged at iter top, drained by the mid-iter barrier after softmax)
// -> 3 blocks/CU.
// ============================================================
__global__ __launch_bounds__(256)
void flash_attn(const unsigned short* __restrict__ qb,
                const unsigned short* __restrict__ kb,
                const unsigned short* __restrict__ vtb,
                float* __restrict__ out)
{
    __shared__ alignas(16) unsigned char smem[49152];   // K dbuf 2x16K | V 16K
    float* Os = (float*)smem;                           // [128][72] epilogue overlay
    unsigned short* Vs = (unsigned short*)(smem + 32768);

    const int tid = threadIdx.x;
    const int qt  = blockIdx.x;   // 0..15 (128 q rows each)
    const int bh  = blockIdx.y;   // 0..63
    const int b   = bh >> 4, h = bh & 15;

    const int w = tid >> 6, lane = tid & 63;
    const int ln = lane & 15, quad = lane >> 4;

    const unsigned short* Qb = qb  + (size_t)bh * T_ * D_;
    const unsigned short* Kb = kb  + (size_t)bh * T_ * D_;
    const unsigned short* Vb = vtb + (size_t)bh * D_ * T_;

    // Q (pre-scaled) as B-operand fragments, 2 subtiles
    const int qrow0 = qt * 128 + w * 16 + ln;
    const bf16x8 qA0 = ld_bf16x8(&Qb[(size_t)qrow0 * D_ + quad * 8]);
    const bf16x8 qA1 = ld_bf16x8(&Qb[(size_t)qrow0 * D_ + 32 + quad * 8]);
    const bf16x8 qB0 = ld_bf16x8(&Qb[(size_t)(qrow0 + 64) * D_ + quad * 8]);
    const bf16x8 qB1 = ld_bf16x8(&Qb[(size_t)(qrow0 + 64) * D_ + 32 + quad * 8]);

    // K staging: instr i -> 8 rows of 128B, swizzled chunks
    const int srow   = lane >> 3;
    const int schunk = (lane & 7) ^ srow;
    const int scu    = schunk * 8;
    // V staging: instr i -> 4 rows of 256B; source chunk swizzled
    const int vrow = lane >> 4;          // 0..3

    const f32x4 fz = {0.f, 0.f, 0.f, 0.f};
    float m2a = -3.0e38f, lia = 0.f;
    float m2b = -3.0e38f, lib = 0.f;
    f32x4 accA[4], accB[4];
#pragma unroll
    for (int dt = 0; dt < 4; ++dt) { accA[dt] = fz; accB[dt] = fz; }

    auto stageK = [&](int kv0, int buf) {
        unsigned short* Ks = (unsigned short*)(smem + buf * 16384);
#pragma unroll
        for (int i = 0; i < 4; ++i) {
            const int kr = kv0 + w * 32 + i * 8 + srow;
            gl_lds16(Kb + (size_t)kr * D_ + scu, Ks + (w * 4 + i) * 512);
        }
    };
    auto stageV = [&](int kv0) {
#pragma unroll
        for (int i = 0; i < 4; ++i) {
            const int dr = (w * 4 + i) * 4 + vrow;
            const int vcs = (lane & 15) ^ ((i & 1) * 4 + vrow);   // src chunk
            gl_lds16(Vb + (size_t)dr * T_ + kv0 + vcs * 8, Vs + (w * 4 + i) * 512);
        }
    };

    stageK(0, 0);   // preload K tile 0

    for (int kv0 = 0; kv0 < T_; kv0 += 128) {
        const int cur = (kv0 >> 7) & 1;
        // barrier A: drains K(cur) prefetch; all waves done with prev V reads
        __syncthreads();
        stageV(kv0);                                      // V for THIS iter
        if (kv0 + 128 < T_) stageK(kv0 + 128, cur ^ 1);   // K for NEXT iter

        const unsigned short* Ks = (const unsigned short*)(smem + cur * 16384);

        // S^T = K · Q^T for both subtiles, sharing K fragments
        f32x4 sA[8], sB[8];
#pragma unroll
        for (int kvt = 0; kvt < 8; ++kvt) {
            const int r_ = kvt * 16 + ln;               // r_&7 == ln&7
            bf16x8 kf0 = ld_bf16x8(&Ks[r_ * 64 + ((quad)     ^ (ln & 7)) * 8]);
            bf16x8 kf1 = ld_bf16x8(&Ks[r_ * 64 + ((quad + 4) ^ (ln & 7)) * 8]);
            f32x4 cA = fz, cB = fz;
            cA = __builtin_amdgcn_mfma_f32_16x16x32_bf16(kf0, qA0, cA, 0, 0, 0);
            cB = __builtin_amdgcn_mfma_f32_16x16x32_bf16(kf0, qB0, cB, 0, 0, 0);
            cA = __builtin_amdgcn_mfma_f32_16x16x32_bf16(kf1, qA1, cA, 0, 0, 0);
            cB = __builtin_amdgcn_mfma_f32_16x16x32_bf16(kf1, qB1, cB, 0, 0, 0);
            sA[kvt] = cA; sB[kvt] = cB;
        }

        // online softmax (log2 domain); P packed directly as 16x16x32 B-frags
        u32x4 pksA[4], pksB[4];
        float alA, alB;
        {
            f32x4 mm = vmax4(vmax4(vmax4(sA[0], sA[1]), vmax4(sA[2], sA[3])),
                             vmax4(vmax4(sA[4], sA[5]), vmax4(sA[6], sA[7])));
            float mx = fmaxf(fmaxf(mm.x, mm.y), fmaxf(mm.z, mm.w));
            mx = fmaxf(mx, __shfl_xor(mx, 16));
            mx = fmaxf(mx, __shfl_xor(mx, 32));
            const float nm = fmaxf(m2a, mx);
            alA = __builtin_amdgcn_exp2f(m2a - nm);
            m2a = nm;
            f32x4 rsv = fz;
#pragma unroll
            for (int p = 0; p < 4; ++p) {
                f32x4 e0, e1;
                e0.x = __builtin_amdgcn_exp2f(sA[2*p].x - m2a);
                e0.y = __builtin_amdgcn_exp2f(sA[2*p].y - m2a);
                e0.z = __builtin_amdgcn_exp2f(sA[2*p].z - m2a);
                e0.w = __builtin_amdgcn_exp2f(sA[2*p].w - m2a);
                e1.x = __builtin_amdgcn_exp2f(sA[2*p+1].x - m2a);
                e1.y = __builtin_amdgcn_exp2f(sA[2*p+1].y - m2a);
                e1.z = __builtin_amdgcn_exp2f(sA[2*p+1].z - m2a);
                e1.w = __builtin_amdgcn_exp2f(sA[2*p+1].w - m2a);
                rsv += e0; rsv += e1;
                pksA[p][0] = pack2bf(e0.x, e0.y);
                pksA[p][1] = pack2bf(e0.z, e0.w);
                pksA[p][2] = pack2bf(e1.x, e1.y);
                pksA[p][3] = pack2bf(e1.z, e1.w);
            }
            float rs = (rsv.x + rsv.y) + (rsv.z + rsv.w);
            rs += __shfl_xor(rs, 16);
            rs += __shfl_xor(rs, 32);
            lia = lia * alA + rs;
        }
        {
            f32x4 mm = vmax4(vmax4(vmax4(sB[0], sB[1]), vmax4(sB[2], sB[3])),
                             vmax4(vmax4(sB[4], sB[5]), vmax4(sB[6], sB[7])));
            float mx = fmaxf(fmaxf(mm.x, mm.y), fmaxf(mm.z, mm.w));
            mx = fmaxf(mx, __shfl_xor(mx, 16));
            mx = fmaxf(mx, __shfl_xor(mx, 32));
            const float nm = fmaxf(m2b, mx);
            alB = __builtin_amdgcn_exp2f(m2b - nm);
            m2b = nm;
            f32x4 rsv = fz;
#pragma unroll
            for (int p = 0; p < 4; ++p) {
                f32x4 e0, e1;
                e0.x = __builtin_amdgcn_exp2f(sB[2*p].x - m2b);
                e0.y = __builtin_amdgcn_exp2f(sB[2*p].y - m2b);
                e0.z = __builtin_amdgcn_exp2f(sB[2*p].z - m2b);
                e0.w = __builtin_amdgcn_exp2f(sB[2*p].w - m2b);
                e1.x = __builtin_amdgcn_exp2f(sB[2*p+1].x - m2b);
                e1.y = __builtin_amdgcn_exp2f(sB[2*p+1].y - m2b);
                e1.z = __builtin_amdgcn_exp2f(sB[2*p+1].z - m2b);
                e1.w = __builtin_amdgcn_exp2f(sB[2*p+1].w - m2b);
                rsv += e0; rsv += e1;
                pksB[p][0] = pack2bf(e0.x, e0.y);
                pksB[p][1] = pack2bf(e0.z, e0.w);
                pksB[p][2] = pack2bf(e1.x, e1.y);
                pksB[p][3] = pack2bf(e1.z, e1.w);
            }
            float rs = (rsv.x + rsv.y) + (rsv.z + rsv.w);
            rs += __shfl_xor(rs, 16);
            rs += __shfl_xor(rs, 32);
            lib = lib * alB + rs;
        }

#pragma unroll
        for (int dt = 0; dt < 4; ++dt) { accA[dt] *= alA; accB[dt] *= alB; }

        // barrier B: drains V(cur) staging (K(next) prefetch also drains,
        // but it had the whole S^T+softmax phase to land)
        __syncthreads();

        // O^T += V^T · P^T via 16x16x32; V frag = one b128, B = pks[p]
#pragma unroll
        for (int dt = 0; dt < 4; ++dt) {
            const int vr = dt * 16 + ln;
#pragma unroll
            for (int p = 0; p < 4; ++p) {
                const int cl = ((p * 4 + quad) ^ (ln & 7));
                bf16x8 vv = ld_bf16x8(&Vs[vr * 128 + cl * 8]);
                accA[dt] = __builtin_amdgcn_mfma_f32_16x16x32_bf16(
                    vv, __builtin_bit_cast(bf16x8, pksA[p]), accA[dt], 0, 0, 0);
                accB[dt] = __builtin_amdgcn_mfma_f32_16x16x32_bf16(
                    vv, __builtin_bit_cast(bf16x8, pksB[p]), accB[dt], 0, 0, 0);
            }
        }
    }

    // epilogue: normalize, transpose O^T -> O via LDS ([128][72] f32)
    __syncthreads();
    const float rva = 1.0f / lia, rvb = 1.0f / lib;
#pragma unroll
    for (int dt = 0; dt < 4; ++dt)
#pragma unroll
        for (int r = 0; r < 4; ++r) {
            Os[(w * 16 + ln) * 72 + dt * 16 + quad * 4 + r]        = accA[dt][r] * rva;
            Os[(64 + w * 16 + ln) * 72 + dt * 16 + quad * 4 + r]   = accB[dt][r] * rvb;
        }
    __syncthreads();

    const int q  = tid >> 1;              // 0..127
    const int c0 = (tid & 1) * 32;
    const float* src = &Os[q * 72 + c0];
    float* dst = &out[((size_t)(b * T_ + qt * 128 + q)) * C_ + h * 64 + c0];
#pragma unroll
    for (int i = 0; i < 8; ++i)
        *(f32x4*)(dst + i * 4) = *(const f32x4*)(src + i * 4);
}

// ============================================================
extern "C" void kernel_launch(void* const* d_in, const int* in_sizes, int n_in,
                              void* d_out, int out_size, void* d_ws, size_t ws_size,
                              hipStream_t stream) {
    const float* q_x = (const float*)d_in[0];
    const float* Wq  = (const float*)d_in[1];
    const float* bq  = (const float*)d_in[2];
    const float* Wk  = (const float*)d_in[3];
    const float* bk  = (const float*)d_in[4];
    const float* Wv  = (const float*)d_in[5];
    const float* bv  = (const float*)d_in[6];
    float* out = (float*)d_out;

    const size_t elems = (size_t)M_ * C_;      // 8,388,608
    unsigned short* xb  = (unsigned short*)d_ws;
    unsigned short* wb  = xb + elems;                    // 3*C*C
    unsigned short* qb  = wb + (size_t)3 * C_ * C_;
    unsigned short* kb  = qb + elems;
    unsigned short* vtb = kb + elems;
    (void)ws_size; (void)in_sizes; (void)n_in; (void)out_size;

    const int64_t total4 = X4_ + 3 * W4_;      // 2,883,584
    cvt_bf16<<<(int)(total4 / 256), 256, 0, stream>>>(q_x, Wq, Wk, Wv, xb, wb);

    qkv_gemm<<<dim3(M_ / 128, 24), 256, 0, stream>>>(
        xb, wb, bq, bk, bv, qb, kb, vtb);

    flash_attn<<<dim3(T_ / 128, B_ * H_), 256, 0, stream>>>(qb, kb, vtb, out);
}